// Round 12
// baseline (1908.176 us; speedup 1.0000x reference)
//
#include <hip/hip_runtime.h>

typedef __attribute__((ext_vector_type(8))) short short8;
typedef __attribute__((ext_vector_type(4))) float f32x4;
typedef __attribute__((ext_vector_type(4))) unsigned int u32x4;
typedef unsigned long long ull;

__device__ __forceinline__ unsigned short f2bf(float f){
  union { float f; unsigned u; } v; v.f = f;
  return (unsigned short)((v.u + 0x7FFFu + ((v.u >> 16) & 1u)) >> 16);
}
__device__ __forceinline__ float fsig(float x){ return 1.f / (1.f + __expf(-x)); }
__device__ __forceinline__ float ftanh(float x){ return 1.f - 2.f / (__expf(2.f * x) + 1.f); }

__device__ __forceinline__ void gld16(const void* g, void* l){
  __builtin_amdgcn_global_load_lds((const __attribute__((address_space(1))) void*)g,
                                   (__attribute__((address_space(3))) void*)l, 16, 0, 0);
}

// ---------- cast & transpose x: [64,256,1024] f32 -> xT[(t*64+b)][1024] bf16
__global__ __launch_bounds__(256) void cast_x_kernel(const float* __restrict__ x,
                                                     unsigned short* __restrict__ xT){
  const int row = blockIdx.x;            // = b*256 + t
  const int b = row >> 8, t = row & 255;
  float4 v = ((const float4*)(x + (size_t)row * 1024))[threadIdx.x];
  ushort4 o; o.x = f2bf(v.x); o.y = f2bf(v.y); o.z = f2bf(v.z); o.w = f2bf(v.w);
  ((ushort4*)(xT + (size_t)(t * 64 + b) * 1024))[threadIdx.x] = o;
}

// ---------- plain f32 -> bf16 cast (W_ih)
__global__ __launch_bounds__(256) void cast_rows_kernel(const float* __restrict__ s,
                                                        unsigned short* __restrict__ d){
  const size_t i = (size_t)blockIdx.x * 256 + threadIdx.x;
  float4 v = ((const float4*)s)[i];
  ushort4 o; o.x = f2bf(v.x); o.y = f2bf(v.y); o.z = f2bf(v.z); o.w = f2bf(v.w);
  ((ushort4*)d)[i] = o;
}

// ---------- x_proj GEMM -> block-chunk layout:
// chunk = (t*4+bt)*64+kt (1024 bf16); element = g*256 + rb*16 + kc
__global__ __launch_bounds__(256) void gemm_xproj_kernel(
    const unsigned short* __restrict__ A,   // xT [16384][1024]
    const unsigned short* __restrict__ W,   // W_ih bf16 [4096][1024]
    const float* __restrict__ bih,
    const float* __restrict__ bhh,
    unsigned short* __restrict__ C){
  __shared__ __align__(16) unsigned short As[2][4096];
  __shared__ __align__(16) unsigned short Bs[2][4096];
  const int tid  = threadIdx.x;
  const int lane = tid & 63;
  const int wv   = tid >> 6;
  const int wr   = wv >> 1, wc = wv & 1;
  const int mBase = blockIdx.y << 7;
  const int nBase = blockIdx.x << 7;
  const int lg4 = lane >> 4, lg15 = lane & 15;

  f32x4 acc[4][4] = {};

  auto stage = [&](int buf, int kk){
    #pragma unroll
    for (int rnd = 0; rnd < 2; ++rnd){
      const int s    = tid + (rnd << 8);
      const int row  = s >> 2;
      const int q    = s & 3;
      const int slog = q ^ (row & 3);
      const size_t col = (size_t)(kk << 5) + (slog << 3);
      unsigned short* dA = &As[buf][(size_t)((wv << 6) + (rnd << 8)) << 3];
      unsigned short* dB = &Bs[buf][(size_t)((wv << 6) + (rnd << 8)) << 3];
      gld16(A + (size_t)(mBase + row) * 1024 + col, dA);
      gld16(W + (size_t)(nBase + row) * 1024 + col, dB);
    }
  };

  stage(0, 0);
  __syncthreads();

  for (int kk = 0; kk < 32; ++kk){
    const int buf = kk & 1;
    if (kk != 31) stage(buf ^ 1, kk + 1);
    short8 af[4], bfr[4];
    #pragma unroll
    for (int mi = 0; mi < 4; ++mi){
      const int row = (wr << 6) + (mi << 4) + lg15;
      const int q   = lg4 ^ (row & 3);
      af[mi] = *(const short8*)&As[buf][(row << 5) + (q << 3)];
    }
    #pragma unroll
    for (int ni = 0; ni < 4; ++ni){
      const int row = (wc << 6) + (ni << 4) + lg15;
      const int q   = lg4 ^ (row & 3);
      bfr[ni] = *(const short8*)&Bs[buf][(row << 5) + (q << 3)];
    }
    #pragma unroll
    for (int mi = 0; mi < 4; ++mi)
      #pragma unroll
      for (int ni = 0; ni < 4; ++ni)
        acc[mi][ni] = __builtin_amdgcn_mfma_f32_16x16x32_bf16(af[mi], bfr[ni], acc[mi][ni], 0, 0, 0);
    __syncthreads();
  }

  #pragma unroll
  for (int ni = 0; ni < 4; ++ni){
    const int gcol = nBase + (wc << 6) + (ni << 4) + lg15;
    const float bsum = bih[gcol] + bhh[gcol];
    const int g = gcol >> 10, kk = gcol & 1023;
    const int ktt = kk >> 4, kc = kk & 15;
    #pragma unroll
    for (int mi = 0; mi < 4; ++mi){
      const int grow0 = mBase + (wr << 6) + (mi << 4) + (lg4 << 2);
      const int t = grow0 >> 6, b = grow0 & 63;
      const int btt = b >> 4, rb0 = b & 15;
      const size_t base = ((size_t)((t * 4 + btt) * 64 + ktt) << 10)
                          + (g << 8) + (rb0 << 4) + kc;
      #pragma unroll
      for (int r = 0; r < 4; ++r)
        C[base + (r << 4)] = f2bf(acc[mi][ni][r] + bsum);
    }
  }
}

// ---------- persistent recurrence: 256 blocks x 64 threads, LDS = 131072 exactly
// Data-polling sync: every stored h halfword is tagged |1 (never 0x0000).
// Layout (u64 units): group = bt<<14, buf = <<12 (4096 u64 = 16 rows x 256),
// row = 256, slice(kt,l15,l4) = l15*256 + kt*4 + l4.
// 4-deep rotating buffers; each block zeroes its OWN slice of buf[(t+1)%4]
// at step-t start (drained by the consume vmcnt(0) before its h-store).
// One init barrier (memset counter each launch) makes replays safe.
__global__ __launch_bounds__(64, 1) void lstm_steps_kernel(
    const float* __restrict__ Whh,            // [4096][1024] f32
    const unsigned short* __restrict__ xproj, // block-chunk layout, bf16
    const float* __restrict__ h0,
    const float* __restrict__ c0,
    const int* __restrict__ dones,            // [64][256] int32
    unsigned short* __restrict__ hbuf,        // [4 grp][4 buf][16][1024] bf16 tagged
    float* __restrict__ out,
    unsigned* __restrict__ bar){              // init barrier: 4 counters, 256B apart
  __shared__ __align__(16) unsigned short Ws[64 * 1024];   // 128 KiB exactly
  const int lane = threadIdx.x;
  const int bt = blockIdx.x >> 6;
  const int kt = blockIdx.x & 63;
  const int b0 = bt << 4, k0 = kt << 4;
  const int l15 = lane & 15;
  const int l4  = lane >> 4;
  ull* hb = (ull*)hbuf + ((size_t)bt << 14);          // group base (16384 u64)
  const ull TAG = 0x0001000100010001ull;
  const size_t myslice = (size_t)l15 * 256 + (kt << 2) + l4;  // u64 idx within a buf
  unsigned* cnt = bar + (bt << 6);

  // ---- prologue: zero my slice of bufs 0,1,2; write tagged h0 into buf 3
  {
    __hip_atomic_store(hb +           myslice, 0ull, __ATOMIC_RELAXED, __HIP_MEMORY_SCOPE_AGENT);
    __hip_atomic_store(hb + 4096    + myslice, 0ull, __ATOMIC_RELAXED, __HIP_MEMORY_SCOPE_AGENT);
    __hip_atomic_store(hb + 8192    + myslice, 0ull, __ATOMIC_RELAXED, __HIP_MEMORY_SCOPE_AGENT);
    const int i = (kt << 6) + lane;          // 0..4095 across the group
    const int row = i >> 8;
    const int c4 = (i & 255) << 2;
    float4 v = *(const float4*)(h0 + (size_t)(b0 + row) * 1024 + c4);
    union { ull q; unsigned short s[4]; } p;
    p.s[0] = f2bf(v.x); p.s[1] = f2bf(v.y); p.s[2] = f2bf(v.z); p.s[3] = f2bf(v.w);
    p.q |= TAG;
    __hip_atomic_store(hb + 12288 + (size_t)row * 256 + (c4 >> 2), p.q,
                       __ATOMIC_RELAXED, __HIP_MEMORY_SCOPE_AGENT);
  }
  asm volatile("s_waitcnt vmcnt(0)" ::: "memory");
  if (lane == 0)
    __hip_atomic_fetch_add(cnt, 1u, __ATOMIC_RELAXED, __HIP_MEMORY_SCOPE_AGENT);

  // ---- stage W_hh slice -> bf16 LDS, XOR-swizzled 16B slots (rows: g*16+j)
  {
    const int wrow = lane;
    const int g = lane >> 4, j = lane & 15;
    const float* src = Whh + ((size_t)(g << 10) + k0 + j) * 1024;
    for (int c = 0; c < 1024; c += 8){
      float4 v0 = *(const float4*)(src + c);
      float4 v1 = *(const float4*)(src + c + 4);
      short8 pk;
      pk[0] = (short)f2bf(v0.x); pk[1] = (short)f2bf(v0.y);
      pk[2] = (short)f2bf(v0.z); pk[3] = (short)f2bf(v0.w);
      pk[4] = (short)f2bf(v1.x); pk[5] = (short)f2bf(v1.y);
      pk[6] = (short)f2bf(v1.z); pk[7] = (short)f2bf(v1.w);
      const int q = (c >> 3) ^ (wrow & 7);
      *(short8*)&Ws[(wrow << 10) + (q << 3)] = pk;
    }
  }

  // ---- pack dones row (b0+l15) into 4 u64 (quarters), shared via shfl
  ull pk0, pk1, pk2, pk3;
  {
    const int* dp = dones + (size_t)(b0 + l15) * 256 + (l4 << 6);
    ull w = 0;
    for (int j = 0; j < 64; ++j) w |= ((ull)(dp[j] != 0)) << j;
    pk0 = __shfl(w, l15);
    pk1 = __shfl(w, 16 + l15);
    pk2 = __shfl(w, 32 + l15);
    pk3 = __shfl(w, 48 + l15);
  }

  // ---- c tile in registers: lane owns (b0+l15, k0+4*l4+r)
  float creg[4];
  {
    float4 cv = *(const float4*)(c0 + (size_t)(b0 + l15) * 1024 + k0 + (l4 << 2));
    creg[0] = cv.x; creg[1] = cv.y; creg[2] = cv.z; creg[3] = cv.w;
  }

  // ---- first x_proj chunk
  const ull* xpb = (const ull*)xproj;
  ull xpc[4];
  {
    const size_t ch0 = ((size_t)(bt * 64 + kt)) << 8;
    #pragma unroll
    for (int g = 0; g < 4; ++g) xpc[g] = xpb[ch0 + (g << 6) + (l15 << 2) + l4];
  }

  // ---- init barrier: all prologue zeroes + h0 writes of this group visible
  if (lane == 0){
    while (__hip_atomic_load(cnt, __ATOMIC_RELAXED, __HIP_MEMORY_SCOPE_AGENT) < 64u)
      __builtin_amdgcn_s_sleep(1);
  }
  asm volatile("" ::: "memory");   // single wave: lanes reconverge; compiler fence only

  union AV { u32x4 u4; short8 v; };

#define LDH(i, OFF) asm volatile("global_load_dwordx4 %0, %1, off offset:" OFF " sc0 sc1" \
    : "=v"(hv[i].u4) : "v"(hbase));
#define RLDH(i, OFF) if (stale & (1u << i)) { asm volatile( \
    "global_load_dwordx4 %0, %1, off offset:" OFF " sc0 sc1" \
    : "=v"(hv[i].u4) : "v"(hbase)); }
#define BAD(i) ((((hv[i].u4.x) & 0xFFFFu) * ((hv[i].u4.z) & 0xFFFFu)) == 0u)
#define CONSUME(KB) \
  _Pragma("unroll") \
  for (int j = 0; j < 8; ++j){ \
    const int ks = ((KB) << 3) + j; \
    _Pragma("unroll") \
    for (int g = 0; g < 4; ++g){ \
      const int wrow = (g << 4) + l15; \
      const int qs = ((ks << 2) + l4) ^ (wrow & 7); \
      const short8 wf = *(const short8*)&Ws[(wrow << 10) + (qs << 3)]; \
      acc[g] = __builtin_amdgcn_mfma_f32_16x16x32_bf16(wf, hv[ks].v, acc[g], 0, 0, 0); \
    } \
  }

  #pragma unroll
  for (int qq = 0; qq < 4; ++qq){
    const ull pkq = (qq == 0) ? pk0 : (qq == 1) ? pk1 : (qq == 2) ? pk2 : pk3;
    for (int t2 = 0; t2 < 64; ++t2){
      const int t = (qq << 6) + t2;
      const int bufR = (t + 3) & 3;   // holds h(t-1)
      const int bufW = t & 3;         // will hold h(t)
      const int bufZ = (t + 1) & 3;   // zero for h(t+1)

      // ---- zero my future-write slice (drained by the vmcnt(0) below)
      __hip_atomic_store(hb + ((size_t)bufZ << 12) + myslice, 0ull,
                         __ATOMIC_RELAXED, __HIP_MEMORY_SCOPE_AGENT);

      // ---- issue 32 coalesced coherent 16B loads of h(t-1): row b0+l15
      AV hv[32];
      const char* hbase = (const char*)(hb + ((size_t)bufR << 12)) +
                          ((size_t)l15 << 11) + (l4 << 4);
      LDH(0,"0")    LDH(1,"64")    LDH(2,"128")   LDH(3,"192")
      LDH(4,"256")  LDH(5,"320")   LDH(6,"384")   LDH(7,"448")
      LDH(8,"512")  LDH(9,"576")   LDH(10,"640")  LDH(11,"704")
      LDH(12,"768") LDH(13,"832")  LDH(14,"896")  LDH(15,"960")
      LDH(16,"1024") LDH(17,"1088") LDH(18,"1152") LDH(19,"1216")
      LDH(20,"1280") LDH(21,"1344") LDH(22,"1408") LDH(23,"1472")
      LDH(24,"1536") LDH(25,"1600") LDH(26,"1664") LDH(27,"1728")
      LDH(28,"1792") LDH(29,"1856") LDH(30,"1920") LDH(31,"1984")
      asm volatile("s_waitcnt vmcnt(0)" ::: "memory");
      __builtin_amdgcn_sched_barrier(0);

      // ---- tag check + retry only stale chunks (bounded: hang insurance)
      unsigned stale = 0;
      #pragma unroll
      for (int c = 0; c < 32; ++c) if (BAD(c)) stale |= (1u << c);
      int guard = 0;
      while (__any((int)(stale != 0u)) && ++guard < 65536){
        RLDH(0,"0")    RLDH(1,"64")    RLDH(2,"128")   RLDH(3,"192")
        RLDH(4,"256")  RLDH(5,"320")   RLDH(6,"384")   RLDH(7,"448")
        RLDH(8,"512")  RLDH(9,"576")   RLDH(10,"640")  RLDH(11,"704")
        RLDH(12,"768") RLDH(13,"832")  RLDH(14,"896")  RLDH(15,"960")
        RLDH(16,"1024") RLDH(17,"1088") RLDH(18,"1152") RLDH(19,"1216")
        RLDH(20,"1280") RLDH(21,"1344") RLDH(22,"1408") RLDH(23,"1472")
        RLDH(24,"1536") RLDH(25,"1600") RLDH(26,"1664") RLDH(27,"1728")
        RLDH(28,"1792") RLDH(29,"1856") RLDH(30,"1920") RLDH(31,"1984")
        asm volatile("s_waitcnt vmcnt(0)" ::: "memory");
        __builtin_amdgcn_sched_barrier(0);
        unsigned ns = 0;
        #pragma unroll
        for (int c = 0; c < 32; ++c)
          if ((stale & (1u << c)) && BAD(c)) ns |= (1u << c);
        stale = ns;
      }

      // ---- acc init from prefetched x_proj chunk
      f32x4 acc[4];
      #pragma unroll
      for (int g = 0; g < 4; ++g){
        union { ull q; unsigned short s[4]; } u; u.q = xpc[g];
        #pragma unroll
        for (int r = 0; r < 4; ++r){
          union { unsigned uu; float f; } w; w.uu = ((unsigned)u.s[r]) << 16;
          acc[g][r] = w.f;
        }
      }

      // ---- 128 MFMAs over K=1024
      CONSUME(0) CONSUME(1) CONSUME(2) CONSUME(3)

      // ---- LSTM cell: lane owns batch row b0+l15, k = k0+4*l4+r
      const float m = ((pkq >> t2) & 1ull) ? 0.f : 1.f;
      float ot4[4], hm4[4];
      unsigned short hb16[4];
      #pragma unroll
      for (int r = 0; r < 4; ++r){
        const float ig = fsig(acc[0][r]);
        const float fg = fsig(acc[1][r]);
        const float gg = ftanh(acc[2][r]);
        const float og = fsig(acc[3][r]);
        const float cn = fg * creg[r] + ig * gg;
        const float hv2 = og * ftanh(cn);
        ot4[r] = ftanh(hv2);
        creg[r] = cn * m;
        const float hm = hv2 * m;
        hm4[r] = hm;
        hb16[r] = f2bf(hm);
      }

      // ---- critical path: tagged h store (no ack, no signal)
      {
        union { ull q; unsigned short s[4]; } p;
        p.s[0] = hb16[0]; p.s[1] = hb16[1]; p.s[2] = hb16[2]; p.s[3] = hb16[3];
        p.q |= TAG;
        __hip_atomic_store(hb + ((size_t)bufW << 12) + myslice, p.q,
                           __ATOMIC_RELAXED, __HIP_MEMORY_SCOPE_AGENT);
      }

      // ---- shadow: out store, finals, next x_proj prefetch
      *(float4*)(out + (size_t)(b0 + l15) * 262144 + ((size_t)t << 10) + k0 + (l4 << 2))
          = make_float4(ot4[0], ot4[1], ot4[2], ot4[3]);
      if (t == 255){
        float* hf = out + 16777216 + (size_t)(b0 + l15) * 1024 + k0 + (l4 << 2);
        float* cf = out + 16842752 + (size_t)(b0 + l15) * 1024 + k0 + (l4 << 2);
        *(float4*)hf = make_float4(hm4[0], hm4[1], hm4[2], hm4[3]);
        *(float4*)cf = make_float4(creg[0], creg[1], creg[2], creg[3]);
      }
      {
        const int tn = (t < 255) ? t + 1 : 255;
        const size_t chn = ((size_t)((tn * 4 + bt) * 64 + kt)) << 8;
        #pragma unroll
        for (int g = 0; g < 4; ++g) xpc[g] = xpb[chn + (g << 6) + (l15 << 2) + l4];
      }
    }
  }
#undef LDH
#undef RLDH
#undef BAD
#undef CONSUME
}

extern "C" void kernel_launch(void* const* d_in, const int* in_sizes, int n_in,
                              void* d_out, int out_size, void* d_ws, size_t ws_size,
                              hipStream_t stream){
  const float* x    = (const float*)d_in[0];
  const float* h0   = (const float*)d_in[1];
  const float* c0   = (const float*)d_in[2];
  const int*   dn   = (const int*)d_in[3];
  const float* Wih  = (const float*)d_in[4];
  const float* Whh  = (const float*)d_in[5];
  const float* bih  = (const float*)d_in[6];
  const float* bhh  = (const float*)d_in[7];
  float* out = (float*)d_out;
  char* ws = (char*)d_ws;

  unsigned short* xT    = (unsigned short*)(ws);               // 33,554,432 B (GEMM phase only)
  unsigned short* Wib   = (unsigned short*)(ws + 33554432);    //  8,388,608 B
  unsigned short* xproj = (unsigned short*)(ws + 41943040);    // 134,217,728 B
  unsigned short* hbuf  = (unsigned short*)(ws + 176160768);   //    524,288 B [4grp][4buf][16][1024]
  unsigned*       bar   = (unsigned*)(ws + 176685056);         //      1,024 B

  cast_x_kernel<<<16384, 256, 0, stream>>>(x, xT);
  cast_rows_kernel<<<4096, 256, 0, stream>>>(Wih, Wib);
  gemm_xproj_kernel<<<dim3(32, 128), 256, 0, stream>>>(xT, Wib, bih, bhh, xproj);
  hipMemsetAsync(bar, 0, 1024, stream);

  const float* Whh_ = Whh; const unsigned short* xp_ = xproj;
  const float* h0_ = h0; const float* c0_ = c0; const int* dn_ = dn;
  unsigned short* hb_ = hbuf; float* out_ = out; unsigned* bar_ = bar;
  void* args[] = {&Whh_, &xp_, &h0_, &c0_, &dn_, &hb_, &out_, &bar_};
  hipError_t ce = hipLaunchCooperativeKernel((void*)lstm_steps_kernel, dim3(256), dim3(64),
                                             args, 0, stream);
  if (ce != hipSuccess){
    // 256 blocks, 1/CU (128 KiB LDS) on a 256-CU device: co-resident in practice
    lstm_steps_kernel<<<256, 64, 0, stream>>>(Whh_, xp_, h0_, c0_, dn_, hb_, out_, bar_);
  }
}

// Round 13
// 1396.782 us; speedup vs baseline: 1.3661x; 1.3661x over previous
//
#include <hip/hip_runtime.h>

typedef __attribute__((ext_vector_type(8))) short short8;
typedef __attribute__((ext_vector_type(4))) float f32x4;
typedef unsigned long long ull;

__device__ __forceinline__ unsigned short f2bf(float f){
  union { float f; unsigned u; } v; v.f = f;
  return (unsigned short)((v.u + 0x7FFFu + ((v.u >> 16) & 1u)) >> 16);
}
__device__ __forceinline__ float bf2f(unsigned short u){
  union { unsigned u; float f; } v; v.u = ((unsigned)u) << 16; return v.f;
}
__device__ __forceinline__ float fsig(float x){ return 1.f / (1.f + __expf(-x)); }
__device__ __forceinline__ float ftanh(float x){ return 1.f - 2.f / (__expf(2.f * x) + 1.f); }

__device__ __forceinline__ void gld16(const void* g, void* l){
  __builtin_amdgcn_global_load_lds((const __attribute__((address_space(1))) void*)g,
                                   (__attribute__((address_space(3))) void*)l, 16, 0, 0);
}

// ---------- merged casts: blocks [0,16384) transpose+cast x; [16384,20480) cast W_ih
__global__ __launch_bounds__(256) void cast_all_kernel(const float* __restrict__ x,
                                                       unsigned short* __restrict__ xT,
                                                       const float* __restrict__ Wih,
                                                       unsigned short* __restrict__ Wib){
  const int bid = blockIdx.x;
  if (bid < 16384){
    const int row = bid;                 // = b*256 + t
    const int b = row >> 8, t = row & 255;
    float4 v = ((const float4*)(x + (size_t)row * 1024))[threadIdx.x];
    ushort4 o; o.x = f2bf(v.x); o.y = f2bf(v.y); o.z = f2bf(v.z); o.w = f2bf(v.w);
    ((ushort4*)(xT + (size_t)(t * 64 + b) * 1024))[threadIdx.x] = o;
  } else {
    const size_t i = (size_t)(bid - 16384) * 256 + threadIdx.x;
    float4 v = ((const float4*)Wih)[i];
    ushort4 o; o.x = f2bf(v.x); o.y = f2bf(v.y); o.z = f2bf(v.z); o.w = f2bf(v.w);
    ((ushort4*)Wib)[i] = o;
  }
}

// ---------- x_proj GEMM -> block-chunk layout:
// chunk = (t*4+bt)*64+kt (1024 bf16); element = g*256 + rb*16 + kc
// XCD-swizzled tile assignment (nwg=4096, 8 XCDs, bijective).
__global__ __launch_bounds__(256) void gemm_xproj_kernel(
    const unsigned short* __restrict__ A,   // xT [16384][1024]
    const unsigned short* __restrict__ W,   // W_ih bf16 [4096][1024]
    const float* __restrict__ bih,
    const float* __restrict__ bhh,
    unsigned short* __restrict__ C){
  __shared__ __align__(16) unsigned short As[2][4096];
  __shared__ __align__(16) unsigned short Bs[2][4096];
  const int tid  = threadIdx.x;
  const int lane = tid & 63;
  const int wv   = tid >> 6;
  const int wr   = wv >> 1, wc = wv & 1;
  const int orig = blockIdx.y * 32 + blockIdx.x;
  const int swz  = (orig & 7) * 512 + (orig >> 3);   // XCD-contiguous chunks
  const int mBase = (swz >> 5) << 7;
  const int nBase = (swz & 31) << 7;
  const int lg4 = lane >> 4, lg15 = lane & 15;

  f32x4 acc[4][4] = {};

  auto stage = [&](int buf, int kk){
    #pragma unroll
    for (int rnd = 0; rnd < 2; ++rnd){
      const int s    = tid + (rnd << 8);
      const int row  = s >> 2;
      const int q    = s & 3;
      const int slog = q ^ (row & 3);
      const size_t col = (size_t)(kk << 5) + (slog << 3);
      unsigned short* dA = &As[buf][(size_t)((wv << 6) + (rnd << 8)) << 3];
      unsigned short* dB = &Bs[buf][(size_t)((wv << 6) + (rnd << 8)) << 3];
      gld16(A + (size_t)(mBase + row) * 1024 + col, dA);
      gld16(W + (size_t)(nBase + row) * 1024 + col, dB);
    }
  };

  stage(0, 0);
  __syncthreads();

  for (int kk = 0; kk < 32; ++kk){
    const int buf = kk & 1;
    if (kk != 31) stage(buf ^ 1, kk + 1);
    short8 af[4], bfr[4];
    #pragma unroll
    for (int mi = 0; mi < 4; ++mi){
      const int row = (wr << 6) + (mi << 4) + lg15;
      const int q   = lg4 ^ (row & 3);
      af[mi] = *(const short8*)&As[buf][(row << 5) + (q << 3)];
    }
    #pragma unroll
    for (int ni = 0; ni < 4; ++ni){
      const int row = (wc << 6) + (ni << 4) + lg15;
      const int q   = lg4 ^ (row & 3);
      bfr[ni] = *(const short8*)&Bs[buf][(row << 5) + (q << 3)];
    }
    #pragma unroll
    for (int mi = 0; mi < 4; ++mi)
      #pragma unroll
      for (int ni = 0; ni < 4; ++ni)
        acc[mi][ni] = __builtin_amdgcn_mfma_f32_16x16x32_bf16(af[mi], bfr[ni], acc[mi][ni], 0, 0, 0);
    __syncthreads();
  }

  #pragma unroll
  for (int ni = 0; ni < 4; ++ni){
    const int gcol = nBase + (wc << 6) + (ni << 4) + lg15;
    const float bsum = bih[gcol] + bhh[gcol];
    const int g = gcol >> 10, kk = gcol & 1023;
    const int ktt = kk >> 4, kc = kk & 15;
    #pragma unroll
    for (int mi = 0; mi < 4; ++mi){
      const int grow0 = mBase + (wr << 6) + (mi << 4) + (lg4 << 2);
      const int t = grow0 >> 6, b = grow0 & 63;
      const int btt = b >> 4, rb0 = b & 15;
      const size_t base = ((size_t)((t * 4 + btt) * 64 + ktt) << 10)
                          + (g << 8) + (rb0 << 4) + kc;
      #pragma unroll
      for (int r = 0; r < 4; ++r)
        C[base + (r << 4)] = f2bf(acc[mi][ni][r] + bsum);
    }
  }
}

// ---------- persistent recurrence: 256 blocks x 64 threads, LDS = 131072 exactly
// (R6 verbatim — empirical best: 4.69 us/step.)
// Critical path per step: poll -> h loads -> MFMA -> cell -> h-store -> vmcnt(0)
// -> signal. out-store / finals / x_proj prefetch are issued AFTER the signal.
__global__ __launch_bounds__(64) void lstm_steps_kernel(
    const float* __restrict__ Whh,            // [4096][1024] f32
    const unsigned short* __restrict__ xproj, // block-chunk layout, bf16
    const float* __restrict__ h0,
    const float* __restrict__ c0,
    const int* __restrict__ dones,            // [64][256] int32
    unsigned short* __restrict__ hbuf,        // [2][64][1024] bf16 (agent-coherent access only)
    float* __restrict__ out,
    unsigned* __restrict__ bar){              // 4 counters, 256B apart
  __shared__ __align__(16) unsigned short Ws[64 * 1024];   // 128 KiB exactly
  const int lane = threadIdx.x;
  const int bt = blockIdx.x >> 6;
  const int kt = blockIdx.x & 63;
  const int b0 = bt << 4, k0 = kt << 4;
  const int l15 = lane & 15;
  const int l4  = lane >> 4;
  unsigned* cnt = bar + (bt << 6);

  // ---- h0 -> hbuf[0] first, then signal init (unblocks the group's ramp)
  {
    const int i = (kt << 6) + lane;          // 0..4095 across the group
    const int row = i >> 8;
    const int c4 = (i & 255) << 2;
    float4 v = *(const float4*)(h0 + (size_t)(b0 + row) * 1024 + c4);
    union { ull q; unsigned short s[4]; } p;
    p.s[0] = f2bf(v.x); p.s[1] = f2bf(v.y); p.s[2] = f2bf(v.z); p.s[3] = f2bf(v.w);
    __hip_atomic_store((ull*)hbuf + (size_t)(b0 + row) * 256 + (c4 >> 2), p.q,
                       __ATOMIC_RELAXED, __HIP_MEMORY_SCOPE_AGENT);
  }
  asm volatile("s_waitcnt vmcnt(0)" ::: "memory");
  if (lane == 0)
    __hip_atomic_fetch_add(cnt, 1u, __ATOMIC_RELAXED, __HIP_MEMORY_SCOPE_AGENT);

  // ---- stage W_hh slice -> bf16 LDS, XOR-swizzled 16B slots (rows: g*16+j)
  {
    const int wrow = lane;
    const int g = lane >> 4, j = lane & 15;
    const float* src = Whh + ((size_t)(g << 10) + k0 + j) * 1024;
    for (int c = 0; c < 1024; c += 8){
      float4 v0 = *(const float4*)(src + c);
      float4 v1 = *(const float4*)(src + c + 4);
      short8 pk;
      pk[0] = (short)f2bf(v0.x); pk[1] = (short)f2bf(v0.y);
      pk[2] = (short)f2bf(v0.z); pk[3] = (short)f2bf(v0.w);
      pk[4] = (short)f2bf(v1.x); pk[5] = (short)f2bf(v1.y);
      pk[6] = (short)f2bf(v1.z); pk[7] = (short)f2bf(v1.w);
      const int q = (c >> 3) ^ (wrow & 7);
      *(short8*)&Ws[(wrow << 10) + (q << 3)] = pk;
    }
  }

  // ---- pack dones row (b0+l15) into 4 u64 (quarters), shared via shfl
  ull pk0, pk1, pk2, pk3;
  {
    const int* dp = dones + (size_t)(b0 + l15) * 256 + (l4 << 6);
    ull w = 0;
    for (int j = 0; j < 64; ++j) w |= ((ull)(dp[j] != 0)) << j;
    pk0 = __shfl(w, l15);
    pk1 = __shfl(w, 16 + l15);
    pk2 = __shfl(w, 32 + l15);
    pk3 = __shfl(w, 48 + l15);
  }

  // ---- c tile in registers: lane owns (b0+l15, k0+4*l4+r)
  float creg[4];
  {
    float4 cv = *(const float4*)(c0 + (size_t)(b0 + l15) * 1024 + k0 + (l4 << 2));
    creg[0] = cv.x; creg[1] = cv.y; creg[2] = cv.z; creg[3] = cv.w;
  }

  // ---- first x_proj chunk
  const ull* xpb = (const ull*)xproj;
  ull xpc[4];
  {
    const size_t ch0 = ((size_t)(bt * 64 + kt)) << 8;
    #pragma unroll
    for (int g = 0; g < 4; ++g) xpc[g] = xpb[ch0 + (g << 6) + (l15 << 2) + l4];
  }

  union AV { ull q[2]; short8 v; };

  #pragma unroll
  for (int qq = 0; qq < 4; ++qq){
    const ull pkq = (qq == 0) ? pk0 : (qq == 1) ? pk1 : (qq == 2) ? pk2 : pk3;
    for (int t2 = 0; t2 < 64; ++t2){
      const int t = (qq << 6) + t2;
      const ull* hc = (const ull*)hbuf + ((size_t)(t & 1) << 14);
      ull* hn = (ull*)hbuf + ((size_t)((t + 1) & 1) << 14);

      // ---- poll: all 64 producers signaled end of step t-1 (counter >= 64*(t+1))
      if (lane == 0){
        const unsigned tgt = ((unsigned)t + 1u) << 6;
        while (__hip_atomic_load(cnt, __ATOMIC_RELAXED, __HIP_MEMORY_SCOPE_AGENT) < tgt)
          __builtin_amdgcn_s_sleep(1);
      }
      asm volatile("" ::: "memory");   // single wave: lanes reconverge; fence compiler only

      // ---- pipelined h loads (row b0+l15, 16B chunk l4, stride 64B per ks)
      const ull* hrow = hc + (size_t)(b0 + l15) * 256 + (l4 << 1);
      AV ha[8], hbv[8];
      auto load8 = [&](AV (&hv)[8], int kb){
        #pragma unroll
        for (int j = 0; j < 8; ++j){
          const int ks = (kb << 3) + j;
          hv[j].q[0] = __hip_atomic_load(hrow + (ks << 3),     __ATOMIC_RELAXED, __HIP_MEMORY_SCOPE_AGENT);
          hv[j].q[1] = __hip_atomic_load(hrow + (ks << 3) + 1, __ATOMIC_RELAXED, __HIP_MEMORY_SCOPE_AGENT);
        }
      };
      f32x4 acc[4];
      auto accinit = [&](){
        #pragma unroll
        for (int g = 0; g < 4; ++g){
          union { ull q; unsigned short s[4]; } u; u.q = xpc[g];
          #pragma unroll
          for (int r = 0; r < 4; ++r) acc[g][r] = bf2f(u.s[r]);
        }
      };
      auto consume = [&](AV (&hv)[8], int kb){
        #pragma unroll
        for (int j = 0; j < 8; ++j){
          const int ks = (kb << 3) + j;
          #pragma unroll
          for (int g = 0; g < 4; ++g){
            const int wrow = (g << 4) + l15;
            const int qs = ((ks << 2) + l4) ^ (wrow & 7);
            const short8 wf = *(const short8*)&Ws[(wrow << 10) + (qs << 3)];
            // A = W fragment, B = h fragment -> D row = gate-k, D col = batch
            acc[g] = __builtin_amdgcn_mfma_f32_16x16x32_bf16(wf, hv[j].v, acc[g], 0, 0, 0);
          }
        }
      };
      load8(ha, 0); load8(hbv, 1);
      accinit();
      consume(ha, 0); load8(ha, 2);
      consume(hbv, 1); load8(hbv, 3);
      consume(ha, 2); consume(hbv, 3);

      // ---- LSTM cell: lane owns batch row b0+l15, k = k0+4*l4+r
      const float m = ((pkq >> t2) & 1ull) ? 0.f : 1.f;
      float ot4[4], hm4[4];
      unsigned short hb16[4];
      #pragma unroll
      for (int r = 0; r < 4; ++r){
        const float ig = fsig(acc[0][r]);
        const float fg = fsig(acc[1][r]);
        const float gg = ftanh(acc[2][r]);
        const float og = fsig(acc[3][r]);
        const float cn = fg * creg[r] + ig * gg;
        const float hv = og * ftanh(cn);
        ot4[r] = ftanh(hv);
        creg[r] = cn * m;
        const float hm = hv * m;
        hm4[r] = hm;
        hb16[r] = f2bf(hm);
      }

      // ---- critical path: h store -> ack -> signal
      {
        union { ull q; unsigned short s[4]; } p;
        p.s[0] = hb16[0]; p.s[1] = hb16[1]; p.s[2] = hb16[2]; p.s[3] = hb16[3];
        __hip_atomic_store(hn + (size_t)(b0 + l15) * 256 + (k0 >> 2) + l4, p.q,
                           __ATOMIC_RELAXED, __HIP_MEMORY_SCOPE_AGENT);
      }
      asm volatile("s_waitcnt vmcnt(0)" ::: "memory");
      if (lane == 0)
        __hip_atomic_fetch_add(cnt, 1u, __ATOMIC_RELAXED, __HIP_MEMORY_SCOPE_AGENT);

      // ---- shadow: out store, finals, next x_proj prefetch
      *(float4*)(out + (size_t)(b0 + l15) * 262144 + ((size_t)t << 10) + k0 + (l4 << 2))
          = make_float4(ot4[0], ot4[1], ot4[2], ot4[3]);
      if (t == 255){
        float* hf = out + 16777216 + (size_t)(b0 + l15) * 1024 + k0 + (l4 << 2);
        float* cf = out + 16842752 + (size_t)(b0 + l15) * 1024 + k0 + (l4 << 2);
        *(float4*)hf = make_float4(hm4[0], hm4[1], hm4[2], hm4[3]);
        *(float4*)cf = make_float4(creg[0], creg[1], creg[2], creg[3]);
      }
      {
        const int tn = (t < 255) ? t + 1 : 255;
        const size_t chn = ((size_t)((tn * 4 + bt) * 64 + kt)) << 8;
        #pragma unroll
        for (int g = 0; g < 4; ++g) xpc[g] = xpb[chn + (g << 6) + (l15 << 2) + l4];
      }
    }
  }
}

extern "C" void kernel_launch(void* const* d_in, const int* in_sizes, int n_in,
                              void* d_out, int out_size, void* d_ws, size_t ws_size,
                              hipStream_t stream){
  const float* x    = (const float*)d_in[0];
  const float* h0   = (const float*)d_in[1];
  const float* c0   = (const float*)d_in[2];
  const int*   dn   = (const int*)d_in[3];
  const float* Wih  = (const float*)d_in[4];
  const float* Whh  = (const float*)d_in[5];
  const float* bih  = (const float*)d_in[6];
  const float* bhh  = (const float*)d_in[7];
  float* out = (float*)d_out;
  char* ws = (char*)d_ws;

  unsigned short* xT    = (unsigned short*)(ws);               // 33,554,432 B
  unsigned short* Wib   = (unsigned short*)(ws + 33554432);    //  8,388,608 B
  unsigned short* xproj = (unsigned short*)(ws + 41943040);    // 134,217,728 B
  unsigned short* hbuf  = (unsigned short*)(ws + 176160768);   //    262,144 B
  unsigned*       bar   = (unsigned*)(ws + 176422912);         //      1,024 B

  cast_all_kernel<<<20480, 256, 0, stream>>>(x, xT, Wih, Wib);
  gemm_xproj_kernel<<<dim3(32, 128), 256, 0, stream>>>(xT, Wib, bih, bhh, xproj);
  hipMemsetAsync(bar, 0, 1024, stream);

  const float* Whh_ = Whh; const unsigned short* xp_ = xproj;
  const float* h0_ = h0; const float* c0_ = c0; const int* dn_ = dn;
  unsigned short* hb_ = hbuf; float* out_ = out; unsigned* bar_ = bar;
  void* args[] = {&Whh_, &xp_, &h0_, &c0_, &dn_, &hb_, &out_, &bar_};
  hipError_t ce = hipLaunchCooperativeKernel((void*)lstm_steps_kernel, dim3(256), dim3(64),
                                             args, 0, stream);
  if (ce != hipSuccess){
    // 256 blocks, 1/CU (128 KiB LDS) on a 256-CU device: co-resident in practice
    lstm_steps_kernel<<<256, 64, 0, stream>>>(Whh_, xp_, h0_, c0_, dn_, hb_, out_, bar_);
  }
}